// Round 5
// baseline (116.529 us; speedup 1.0000x reference)
//
#include <hip/hip_runtime.h>

#define LOG2E 1.4426950408889634f

typedef short bf16x8 __attribute__((ext_vector_type(8)));
typedef short short4v __attribute__((ext_vector_type(4)));
typedef float f32x4 __attribute__((ext_vector_type(4)));
typedef _Float16 half4v __attribute__((ext_vector_type(4)));
typedef unsigned u32x4 __attribute__((ext_vector_type(4)));
typedef unsigned __attribute__((address_space(1))) u32g;
typedef unsigned __attribute__((address_space(3))) u32l;

#define MFMA16(a, b, c) __builtin_amdgcn_mfma_f32_16x16x32_bf16((a), (b), (c), 0, 0, 0)

__device__ __forceinline__ short f2bf(float f) {
  unsigned u = __builtin_bit_cast(unsigned, f);
  u += 0x7FFFu + ((u >> 16) & 1u);
  return (short)(u >> 16);
}

__device__ __forceinline__ unsigned cvtpk(float lo, float hi) {
  unsigned r;
  asm("v_cvt_pk_bf16_f32 %0, %1, %2" : "=v"(r) : "v"(lo), "v"(hi));
  return r;
}

__device__ __forceinline__ void g2l16(void* lds, const void* g) {
  __builtin_amdgcn_global_load_lds((u32g*)const_cast<void*>(g), (u32l*)lds, 16, 0, 0);
}

// ---------------------------------------------------------------------------
// GroupNorm: x (B,512,1024) f32 -> xn_t (B,1024,512) bf16   [transposed for GEMM]
// ---------------------------------------------------------------------------
__global__ __launch_bounds__(256) void gn_kernel(const float* __restrict__ x,
                                                 const float* __restrict__ gamma,
                                                 const float* __restrict__ beta,
                                                 short* __restrict__ xn_t) {
  __shared__ _Float16 xs[16 * 1024];  // 32 KB, row = channel, swizzled
  __shared__ float red[8];
  const int bg = blockIdx.x;
  const int b = bg >> 5, g = bg & 31;
  const int t = threadIdx.x;
  const float4* gx4 = (const float4*)(x + (size_t)(b * 512 + g * 16) * 1024);
  float s1 = 0.f, s2 = 0.f;
  for (int i = 0; i < 16; ++i) {
    float4 v = gx4[t + 256 * i];
    s1 += (v.x + v.y) + (v.z + v.w);
    s2 += (v.x * v.x + v.y * v.y) + (v.z * v.z + v.w * v.w);
    half4v pk = {(_Float16)v.x, (_Float16)v.y, (_Float16)v.z, (_Float16)v.w};
    *(half4v*)((char*)xs + i * 2048 + ((8 * t) ^ ((i & 7) << 4))) = pk;
  }
  for (int m = 1; m < 64; m <<= 1) {
    s1 += __shfl_xor(s1, m);
    s2 += __shfl_xor(s2, m);
  }
  if ((t & 63) == 0) {
    red[(t >> 6) * 2] = s1;
    red[(t >> 6) * 2 + 1] = s2;
  }
  __syncthreads();
  s1 = (red[0] + red[2]) + (red[4] + red[6]);
  s2 = (red[1] + red[3]) + (red[5] + red[7]);
  const float mean = s1 * (1.f / 16384.f);
  const float var = s2 * (1.f / 16384.f) - mean * mean;
  const float rstd = rsqrtf(var + 1e-6f);
  const int ci = t & 15;
  const float ga = gamma[g * 16 + ci] * rstd;
  const float be = beta[g * 16 + ci] - mean * ga;
  short* dst = xn_t + (size_t)b * 1024 * 512 + g * 16 + ci;
  const int sw = (ci & 7) << 4;
  for (int i = 0; i < 64; ++i) {
    int n = (t >> 4) + 16 * i;
    float v = (float)*(const _Float16*)((const char*)xs + ci * 2048 + ((2 * n) ^ sw));
    dst[(size_t)n * 512] = f2bf(fmaf(v, ga, be));
  }
}

// ---------------------------------------------------------------------------
__global__ __launch_bounds__(256) void f2bf_kernel(const float* __restrict__ src,
                                                   short* __restrict__ dst, int n4) {
  int i = blockIdx.x * 256 + threadIdx.x;
  if (i < n4) {
    float4 v = ((const float4*)src)[i];
    short4v o = {f2bf(v.x), f2bf(v.y), f2bf(v.z), f2bf(v.w)};
    *(short4v*)(dst + (size_t)i * 4) = o;
  }
}

// ---------------------------------------------------------------------------
// QKV GEMM (m97 structure)
// ---------------------------------------------------------------------------
__global__ __launch_bounds__(256) void qkv_gemm(const short* __restrict__ W,
                                                const short* __restrict__ xn,
                                                const float* __restrict__ bias,
                                                short* __restrict__ qbuf,
                                                short* __restrict__ kbuf,
                                                short* __restrict__ vtbuf) {
  __shared__ short a_sm[128 * 32];
  __shared__ short b_sm[128 * 32];
  const int t = threadIdx.x;
  const int lane = t & 63, w = t >> 6;
  const int nbase = blockIdx.x * 128;
  const int mbase = blockIdx.y * 128;
  const int b = blockIdx.z;
  const short* Asrc = W + (size_t)mbase * 512;
  const short* Bsrc = xn + (size_t)b * 1024 * 512 + (size_t)nbase * 512;

  const int j0 = (w * 2) * 64 + lane;
  const int j1 = j0 + 64;
  const int r0 = j0 >> 2, c0 = (j0 & 3) * 8;
  const int r1 = j1 >> 2, c1 = (j1 & 3) * 8;

  const int wm = (w >> 1) * 64, wn = (w & 1) * 64;
  const int col = lane & 15, rg = lane >> 4, koff = rg * 8;

  f32x4 acc[4][4] = {};

  for (int kt = 0; kt < 16; ++kt) {
    const int k0 = kt * 32;
    g2l16(&a_sm[(w * 2) * 512], Asrc + (size_t)r0 * 512 + k0 + c0);
    g2l16(&a_sm[(w * 2 + 1) * 512], Asrc + (size_t)r1 * 512 + k0 + c1);
    g2l16(&b_sm[(w * 2) * 512], Bsrc + (size_t)r0 * 512 + k0 + c0);
    g2l16(&b_sm[(w * 2 + 1) * 512], Bsrc + (size_t)r1 * 512 + k0 + c1);
    __syncthreads();
    bf16x8 af[4], bfr[4];
    for (int mf = 0; mf < 4; ++mf)
      af[mf] = *(const bf16x8*)&a_sm[(wm + mf * 16 + col) * 32 + koff];
    for (int nf = 0; nf < 4; ++nf)
      bfr[nf] = *(const bf16x8*)&b_sm[(wn + nf * 16 + col) * 32 + koff];
    for (int mf = 0; mf < 4; ++mf)
      for (int nf = 0; nf < 4; ++nf)
        acc[mf][nf] = MFMA16(af[mf], bfr[nf], acc[mf][nf]);
    __syncthreads();
  }

  const int section = mbase >> 9;
  for (int mf = 0; mf < 4; ++mf) {
    const int o0 = mbase + wm + mf * 16 + rg * 4;
    const int h = (o0 >> 6) & 7, d0 = o0 & 63;
    float b4[4];
    for (int r = 0; r < 4; ++r) b4[r] = bias[o0 + r];
    for (int nf = 0; nf < 4; ++nf) {
      const int n = nbase + wn + nf * 16 + col;
      if (section < 2) {
        short4v pk;
        for (int r = 0; r < 4; ++r) pk[r] = f2bf(acc[mf][nf][r] + b4[r]);
        short* dst = (section == 0) ? qbuf : kbuf;
        *(short4v*)&dst[((size_t)(b * 8 + h) * 1024 + n) * 64 + d0] = pk;
      } else {
        for (int r = 0; r < 4; ++r)
          vtbuf[((size_t)(b * 8 + h) * 64 + d0 + r) * 1024 + n] =
              f2bf(acc[mf][nf][r] + b4[r]);
      }
    }
  }
}

// ---------------------------------------------------------------------------
// Flash attention, swapped-operand, 32 q-rows/wave, 4-wave blocks.
// Block = (bh, qt): 4 waves x 32 q-rows = 128-row q-tile; grid (64,8) = 512
// blocks -> 2 blocks/CU so independent blocks hide each other's barriers.
// K fragments read ONCE and shared by both Q fragments (halved K LDS reads).
// V staged column-permuted (u' = rg*8 + hi*4 + r) -> PV A-fragment is one
// full-bank b128 read; P B-fragment stays lane-local (cvt_pk regs).
// setprio around MFMA clusters; defer-max rescale (THR=8).
// ---------------------------------------------------------------------------
__global__ __launch_bounds__(256, 2) void attn_kernel(const short* __restrict__ qbuf,
                                                      const short* __restrict__ kbuf,
                                                      const short* __restrict__ vtbuf,
                                                      short* __restrict__ ao) {
  __shared__ short k_sm[2][128 * 64];  // 2 x 16 KB, row = kv, XOR-swizzled
  __shared__ short v_sm[2][64 * 128];  // 2 x 16 KB, row = d, permuted+swizzled
  const int t = threadIdx.x, lane = t & 63, w = t >> 6;
  const int col = lane & 15, rg = lane >> 4;
  const int bh = blockIdx.x, qt = blockIdx.y;
  const int b = bh >> 3, h = bh & 7;
  const int qbase = qt * 128 + w * 32;

  // Q fragments (B-operand): aq[mf][kc], lane col = q, k = d
  bf16x8 aq[2][2];
  {
    const short* qp = qbuf + ((size_t)bh * 1024 + qbase) * 64;
#pragma unroll
    for (int mf = 0; mf < 2; ++mf)
#pragma unroll
      for (int kc = 0; kc < 2; ++kc)
        aq[mf][kc] = *(const bf16x8*)&qp[(mf * 16 + col) * 64 + kc * 32 + rg * 8];
  }

  const short* kp0 = kbuf + (size_t)bh * 65536;
  const short* vp0 = vtbuf + (size_t)bh * 65536;

  uint4 kr[4], vr[4];
#define LOADK(kt)                                                                   \
  _Pragma("unroll") for (int i = 0; i < 4; ++i) {                                   \
    int j = t + 256 * i;                                                            \
    kr[i] = *(const uint4*)&kp0[((size_t)(kt)*128 + (j >> 3)) * 64 + (j & 7) * 8];  \
  }
#define LOADV(kt)                                                                   \
  _Pragma("unroll") for (int i = 0; i < 4; ++i) {                                   \
    int j = t + 256 * i;                                                            \
    vr[i] = *(const uint4*)&vp0[(size_t)(j >> 4) * 1024 + (kt)*128 + (j & 15) * 8]; \
  }
#define WRITEK(bi)                                                                  \
  _Pragma("unroll") for (int i = 0; i < 4; ++i) {                                   \
    int j = t + 256 * i;                                                            \
    int row = j >> 3, off = j & 7;                                                  \
    *(uint4*)((char*)k_sm[bi] + row * 128 + ((off * 16) ^ ((row & 7) << 4))) = kr[i]; \
  }
#define WRITEV(bi)                                                                  \
  _Pragma("unroll") for (int i = 0; i < 4; ++i) {                                   \
    int j = t + 256 * i;                                                            \
    int d = j >> 4, g = j & 15;                                                     \
    int base = (g >> 2) * 64 + (g & 1) * 32 + ((g >> 1) & 1) * 8;                   \
    char* vb = (char*)v_sm[bi] + d * 256;                                           \
    uint2 lo = {vr[i].x, vr[i].y}, hi = {vr[i].z, vr[i].w};                         \
    *(uint2*)(vb + ((base) ^ ((d & 7) << 4))) = lo;                                 \
    *(uint2*)(vb + ((base + 16) ^ ((d & 7) << 4))) = hi;                            \
  }

  LOADK(0) LOADV(0) WRITEK(0) WRITEV(0)

  f32x4 oacc[2][4] = {};
  float mrun[2] = {-3e38f, -3e38f}, lrun[2] = {0.f, 0.f};
  const float kSL2E = 0.125f * LOG2E;  // attn scale folded into log2 domain
  int cur = 0;

  for (int kt = 0; kt < 8; ++kt) {
    if (kt < 7) { LOADK(kt + 1) LOADV(kt + 1) }
    __syncthreads();

    // S^T = K * Q^T : K fragment read once, shared by both mf.
    f32x4 sT[2][8];
    __builtin_amdgcn_s_setprio(1);
#pragma unroll
    for (int nf = 0; nf < 8; ++nf) {
      const int n = nf * 16 + col;
      const char* kb = (const char*)k_sm[cur] + n * 128;
      const int sw = (n & 7) << 4;
      bf16x8 bk0 = *(const bf16x8*)(kb + ((rg * 16) ^ sw));
      bf16x8 bk1 = *(const bf16x8*)(kb + ((64 + rg * 16) ^ sw));
#pragma unroll
      for (int mf = 0; mf < 2; ++mf) {
        f32x4 z = {};
        z = MFMA16(bk0, aq[mf][0], z);
        sT[mf][nf] = MFMA16(bk1, aq[mf][1], z);
      }
    }
    __builtin_amdgcn_s_setprio(0);

    unsigned pk[2][8][2];
#pragma unroll
    for (int mf = 0; mf < 2; ++mf) {
      // online softmax: 4 parallel max chains + 2 cross-rg shuffles
      f32x4 mv = sT[mf][0];
#pragma unroll
      for (int nf = 1; nf < 8; ++nf)
#pragma unroll
        for (int r = 0; r < 4; ++r) mv[r] = fmaxf(mv[r], sT[mf][nf][r]);
      float mx = fmaxf(fmaxf(mv[0], mv[1]), fmaxf(mv[2], mv[3]));
      mx = fmaxf(mx, __shfl_xor(mx, 16));
      mx = fmaxf(mx, __shfl_xor(mx, 32));
      const float pmax = mx * 0.125f;
      // defer-max: only rescale when the running max grew by > 8
      if (!__all(pmax <= mrun[mf] + 8.f)) {
        const float mnew = fmaxf(mrun[mf], pmax);
        const float alpha = __builtin_amdgcn_exp2f((mrun[mf] - mnew) * LOG2E);
        mrun[mf] = mnew;
        lrun[mf] *= alpha;
#pragma unroll
        for (int df = 0; df < 4; ++df) oacc[mf][df] *= alpha;
      }
      const float nege = mrun[mf] * LOG2E;
      float psum = 0.f;
#pragma unroll
      for (int nf = 0; nf < 8; ++nf) {
        float p0 = __builtin_amdgcn_exp2f(fmaf(sT[mf][nf][0], kSL2E, -nege));
        float p1 = __builtin_amdgcn_exp2f(fmaf(sT[mf][nf][1], kSL2E, -nege));
        float p2 = __builtin_amdgcn_exp2f(fmaf(sT[mf][nf][2], kSL2E, -nege));
        float p3 = __builtin_amdgcn_exp2f(fmaf(sT[mf][nf][3], kSL2E, -nege));
        psum += (p0 + p1) + (p2 + p3);
        pk[mf][nf][0] = cvtpk(p0, p1);
        pk[mf][nf][1] = cvtpk(p2, p3);
      }
      psum += __shfl_xor(psum, 16);
      psum += __shfl_xor(psum, 32);
      lrun[mf] += psum;
    }

    // O^T += V^T * P^T : shared V b128 read feeds both Q-fragments' MFMAs
    __builtin_amdgcn_s_setprio(1);
#pragma unroll
    for (int kc = 0; kc < 4; ++kc) {
      bf16x8 pb[2];
#pragma unroll
      for (int mf = 0; mf < 2; ++mf) {
        u32x4 pbu = {pk[mf][2 * kc][0], pk[mf][2 * kc][1], pk[mf][2 * kc + 1][0],
                     pk[mf][2 * kc + 1][1]};
        pb[mf] = __builtin_bit_cast(bf16x8, pbu);
      }
#pragma unroll
      for (int df = 0; df < 4; ++df) {
        const int d = df * 16 + col;
        bf16x8 av = *(const bf16x8*)((const char*)v_sm[cur] + d * 256 +
                                     ((kc * 64 + rg * 16) ^ ((d & 7) << 4)));
#pragma unroll
        for (int mf = 0; mf < 2; ++mf) oacc[mf][df] = MFMA16(av, pb[mf], oacc[mf][df]);
      }
    }
    __builtin_amdgcn_s_setprio(0);

    if (kt < 7) { WRITEK(cur ^ 1) WRITEV(cur ^ 1) }
    cur ^= 1;
  }

  // epilogue: O[q][d = df*16 + rg*4 + r], lane-local 1/l scale
#pragma unroll
  for (int mf = 0; mf < 2; ++mf) {
    const float rl = 1.f / lrun[mf];
    const int q = qbase + mf * 16 + col;
    short* dst = ao + ((size_t)b * 1024 + q) * 512 + h * 64;
#pragma unroll
    for (int df = 0; df < 4; ++df) {
      short4v pkv;
#pragma unroll
      for (int r = 0; r < 4; ++r) pkv[r] = f2bf(oacc[mf][df][r] * rl);
      *(short4v*)&dst[df * 16 + rg * 4] = pkv;
    }
  }
#undef LOADK
#undef LOADV
#undef WRITEK
#undef WRITEV
}

// ---------------------------------------------------------------------------
// Proj GEMM + bias + fp32 residual: out = x + W_proj @ ao
// ---------------------------------------------------------------------------
__global__ __launch_bounds__(256) void proj_gemm(const short* __restrict__ W,
                                                 const short* __restrict__ ao,
                                                 const float* __restrict__ bias,
                                                 const float* __restrict__ x,
                                                 float* __restrict__ out) {
  __shared__ short a_sm[128 * 32];
  __shared__ short b_sm[128 * 32];
  const int t = threadIdx.x;
  const int lane = t & 63, w = t >> 6;
  const int nbase = blockIdx.x * 128;
  const int mbase = blockIdx.y * 128;
  const int b = blockIdx.z;
  const short* Asrc = W + (size_t)mbase * 512;
  const short* Bsrc = ao + (size_t)b * 1024 * 512 + (size_t)nbase * 512;

  const int j0 = (w * 2) * 64 + lane;
  const int j1 = j0 + 64;
  const int r0 = j0 >> 2, c0 = (j0 & 3) * 8;
  const int r1 = j1 >> 2, c1 = (j1 & 3) * 8;

  const int wm = (w >> 1) * 64, wn = (w & 1) * 64;
  const int col = lane & 15, rg = lane >> 4, koff = rg * 8;

  f32x4 acc[4][4] = {};

  for (int kt = 0; kt < 16; ++kt) {
    const int k0 = kt * 32;
    g2l16(&a_sm[(w * 2) * 512], Asrc + (size_t)r0 * 512 + k0 + c0);
    g2l16(&a_sm[(w * 2 + 1) * 512], Asrc + (size_t)r1 * 512 + k0 + c1);
    g2l16(&b_sm[(w * 2) * 512], Bsrc + (size_t)r0 * 512 + k0 + c0);
    g2l16(&b_sm[(w * 2 + 1) * 512], Bsrc + (size_t)r1 * 512 + k0 + c1);
    __syncthreads();
    bf16x8 af[4], bfr[4];
    for (int mf = 0; mf < 4; ++mf)
      af[mf] = *(const bf16x8*)&a_sm[(wm + mf * 16 + col) * 32 + koff];
    for (int nf = 0; nf < 4; ++nf)
      bfr[nf] = *(const bf16x8*)&b_sm[(wn + nf * 16 + col) * 32 + koff];
    for (int mf = 0; mf < 4; ++mf)
      for (int nf = 0; nf < 4; ++nf)
        acc[mf][nf] = MFMA16(af[mf], bfr[nf], acc[mf][nf]);
    __syncthreads();
  }

  for (int mf = 0; mf < 4; ++mf) {
    const int o0 = mbase + wm + mf * 16 + rg * 4;
    float b4[4];
    for (int r = 0; r < 4; ++r) b4[r] = bias[o0 + r];
    for (int nf = 0; nf < 4; ++nf) {
      const int n = nbase + wn + nf * 16 + col;
      for (int r = 0; r < 4; ++r) {
        size_t idx = ((size_t)b * 512 + o0 + r) * 1024 + n;
        out[idx] = x[idx] + acc[mf][nf][r] + b4[r];
      }
    }
  }
}

// ---------------------------------------------------------------------------
extern "C" void kernel_launch(void* const* d_in, const int* in_sizes, int n_in,
                              void* d_out, int out_size, void* d_ws, size_t ws_size,
                              hipStream_t stream) {
  const float* x = (const float*)d_in[0];
  const float* gamma = (const float*)d_in[1];
  const float* beta = (const float*)d_in[2];
  const float* w_qkv = (const float*)d_in[3];
  const float* b_qkv = (const float*)d_in[4];
  const float* w_proj = (const float*)d_in[5];
  const float* b_proj = (const float*)d_in[6];
  float* out = (float*)d_out;

  char* ws = (char*)d_ws;
  short* xn_t = (short*)(ws);                  // 8 MB   (B,N,C) bf16
  short* wqkv_b = (short*)(ws + 8388608);      // 1.5 MB
  short* wproj_b = (short*)(ws + 9961472);     // 0.5 MB
  short* qbuf = (short*)(ws + 10485760);       // 8 MB   (BH,N,d)
  short* kbuf = (short*)(ws + 18874368);       // 8 MB   (BH,N,d)
  short* vtbuf = (short*)(ws + 27262976);      // 8 MB   (BH,d,N)
  short* aobuf = (short*)(ws + 35651584);      // 8 MB   (B,N,C)

  gn_kernel<<<dim3(256), dim3(256), 0, stream>>>(x, gamma, beta, xn_t);
  f2bf_kernel<<<dim3(768), dim3(256), 0, stream>>>(w_qkv, wqkv_b, 196608);
  f2bf_kernel<<<dim3(256), dim3(256), 0, stream>>>(w_proj, wproj_b, 65536);
  qkv_gemm<<<dim3(8, 12, 8), dim3(256), 0, stream>>>(wqkv_b, xn_t, b_qkv, qbuf, kbuf,
                                                     vtbuf);
  attn_kernel<<<dim3(64, 8), dim3(256), 0, stream>>>(qbuf, kbuf, vtbuf, aobuf);
  proj_gemm<<<dim3(8, 4, 8), dim3(256), 0, stream>>>(wproj_b, aobuf, b_proj, x, out);
}

// Round 6
// 96.442 us; speedup vs baseline: 1.2083x; 1.2083x over previous
//
#include <hip/hip_runtime.h>

#define LOG2E 1.4426950408889634f

typedef short bf16x8 __attribute__((ext_vector_type(8)));
typedef short short4v __attribute__((ext_vector_type(4)));
typedef float f32x4 __attribute__((ext_vector_type(4)));
typedef _Float16 half4v __attribute__((ext_vector_type(4)));
typedef unsigned u32x4 __attribute__((ext_vector_type(4)));
typedef unsigned __attribute__((address_space(1))) u32g;
typedef unsigned __attribute__((address_space(3))) u32l;

#define MFMA16(a, b, c) __builtin_amdgcn_mfma_f32_16x16x32_bf16((a), (b), (c), 0, 0, 0)

__device__ __forceinline__ short f2bf(float f) {
  unsigned u = __builtin_bit_cast(unsigned, f);
  u += 0x7FFFu + ((u >> 16) & 1u);
  return (short)(u >> 16);
}

__device__ __forceinline__ unsigned cvtpk(float lo, float hi) {
  unsigned r;
  asm("v_cvt_pk_bf16_f32 %0, %1, %2" : "=v"(r) : "v"(lo), "v"(hi));
  return r;
}

__device__ __forceinline__ void g2l16(void* lds, const void* g) {
  __builtin_amdgcn_global_load_lds((u32g*)const_cast<void*>(g), (u32l*)lds, 16, 0, 0);
}

// ---------------------------------------------------------------------------
// GroupNorm: x (B,512,1024) f32 -> xn_t (B,1024,512) bf16   [transposed for GEMM]
// ---------------------------------------------------------------------------
__global__ __launch_bounds__(256) void gn_kernel(const float* __restrict__ x,
                                                 const float* __restrict__ gamma,
                                                 const float* __restrict__ beta,
                                                 short* __restrict__ xn_t) {
  __shared__ _Float16 xs[16 * 1024];  // 32 KB, row = channel, swizzled
  __shared__ float red[8];
  const int bg = blockIdx.x;
  const int b = bg >> 5, g = bg & 31;
  const int t = threadIdx.x;
  const float4* gx4 = (const float4*)(x + (size_t)(b * 512 + g * 16) * 1024);
  float s1 = 0.f, s2 = 0.f;
  for (int i = 0; i < 16; ++i) {
    float4 v = gx4[t + 256 * i];
    s1 += (v.x + v.y) + (v.z + v.w);
    s2 += (v.x * v.x + v.y * v.y) + (v.z * v.z + v.w * v.w);
    half4v pk = {(_Float16)v.x, (_Float16)v.y, (_Float16)v.z, (_Float16)v.w};
    *(half4v*)((char*)xs + i * 2048 + ((8 * t) ^ ((i & 7) << 4))) = pk;
  }
  for (int m = 1; m < 64; m <<= 1) {
    s1 += __shfl_xor(s1, m);
    s2 += __shfl_xor(s2, m);
  }
  if ((t & 63) == 0) {
    red[(t >> 6) * 2] = s1;
    red[(t >> 6) * 2 + 1] = s2;
  }
  __syncthreads();
  s1 = (red[0] + red[2]) + (red[4] + red[6]);
  s2 = (red[1] + red[3]) + (red[5] + red[7]);
  const float mean = s1 * (1.f / 16384.f);
  const float var = s2 * (1.f / 16384.f) - mean * mean;
  const float rstd = rsqrtf(var + 1e-6f);
  const int ci = t & 15;
  const float ga = gamma[g * 16 + ci] * rstd;
  const float be = beta[g * 16 + ci] - mean * ga;
  short* dst = xn_t + (size_t)b * 1024 * 512 + g * 16 + ci;
  const int sw = (ci & 7) << 4;
  for (int i = 0; i < 64; ++i) {
    int n = (t >> 4) + 16 * i;
    float v = (float)*(const _Float16*)((const char*)xs + ci * 2048 + ((2 * n) ^ sw));
    dst[(size_t)n * 512] = f2bf(fmaf(v, ga, be));
  }
}

// ---------------------------------------------------------------------------
__global__ __launch_bounds__(256) void f2bf_kernel(const float* __restrict__ src,
                                                   short* __restrict__ dst, int n4) {
  int i = blockIdx.x * 256 + threadIdx.x;
  if (i < n4) {
    float4 v = ((const float4*)src)[i];
    short4v o = {f2bf(v.x), f2bf(v.y), f2bf(v.z), f2bf(v.w)};
    *(short4v*)(dst + (size_t)i * 4) = o;
  }
}

// ---------------------------------------------------------------------------
// QKV GEMM (m97 structure)
// ---------------------------------------------------------------------------
__global__ __launch_bounds__(256) void qkv_gemm(const short* __restrict__ W,
                                                const short* __restrict__ xn,
                                                const float* __restrict__ bias,
                                                short* __restrict__ qbuf,
                                                short* __restrict__ kbuf,
                                                short* __restrict__ vtbuf) {
  __shared__ short a_sm[128 * 32];
  __shared__ short b_sm[128 * 32];
  const int t = threadIdx.x;
  const int lane = t & 63, w = t >> 6;
  const int nbase = blockIdx.x * 128;
  const int mbase = blockIdx.y * 128;
  const int b = blockIdx.z;
  const short* Asrc = W + (size_t)mbase * 512;
  const short* Bsrc = xn + (size_t)b * 1024 * 512 + (size_t)nbase * 512;

  const int j0 = (w * 2) * 64 + lane;
  const int j1 = j0 + 64;
  const int r0 = j0 >> 2, c0 = (j0 & 3) * 8;
  const int r1 = j1 >> 2, c1 = (j1 & 3) * 8;

  const int wm = (w >> 1) * 64, wn = (w & 1) * 64;
  const int col = lane & 15, rg = lane >> 4, koff = rg * 8;

  f32x4 acc[4][4] = {};

  for (int kt = 0; kt < 16; ++kt) {
    const int k0 = kt * 32;
    g2l16(&a_sm[(w * 2) * 512], Asrc + (size_t)r0 * 512 + k0 + c0);
    g2l16(&a_sm[(w * 2 + 1) * 512], Asrc + (size_t)r1 * 512 + k0 + c1);
    g2l16(&b_sm[(w * 2) * 512], Bsrc + (size_t)r0 * 512 + k0 + c0);
    g2l16(&b_sm[(w * 2 + 1) * 512], Bsrc + (size_t)r1 * 512 + k0 + c1);
    __syncthreads();
    bf16x8 af[4], bfr[4];
    for (int mf = 0; mf < 4; ++mf)
      af[mf] = *(const bf16x8*)&a_sm[(wm + mf * 16 + col) * 32 + koff];
    for (int nf = 0; nf < 4; ++nf)
      bfr[nf] = *(const bf16x8*)&b_sm[(wn + nf * 16 + col) * 32 + koff];
    for (int mf = 0; mf < 4; ++mf)
      for (int nf = 0; nf < 4; ++nf)
        acc[mf][nf] = MFMA16(af[mf], bfr[nf], acc[mf][nf]);
    __syncthreads();
  }

  const int section = mbase >> 9;
  for (int mf = 0; mf < 4; ++mf) {
    const int o0 = mbase + wm + mf * 16 + rg * 4;
    const int h = (o0 >> 6) & 7, d0 = o0 & 63;
    float b4[4];
    for (int r = 0; r < 4; ++r) b4[r] = bias[o0 + r];
    for (int nf = 0; nf < 4; ++nf) {
      const int n = nbase + wn + nf * 16 + col;
      if (section < 2) {
        short4v pk;
        for (int r = 0; r < 4; ++r) pk[r] = f2bf(acc[mf][nf][r] + b4[r]);
        short* dst = (section == 0) ? qbuf : kbuf;
        *(short4v*)&dst[((size_t)(b * 8 + h) * 1024 + n) * 64 + d0] = pk;
      } else {
        for (int r = 0; r < 4; ++r)
          vtbuf[((size_t)(b * 8 + h) * 64 + d0 + r) * 1024 + n] =
              f2bf(acc[mf][nf][r] + b4[r]);
      }
    }
  }
}

// ---------------------------------------------------------------------------
// Flash attention, swapped-operand, 32 q-rows/wave, 4-wave blocks, KV-tile 64.
// LDS = 32 KB/block (2x(8+8) KB double-buffered) -> 4-5 blocks/CU = 16-20
// waves/CU, vs 8 before: latency hiding via occupancy, not block count.
// K fragments read once, shared by both Q fragments. V staged column-permuted
// (u' = rg*8 + hi*4 + r) -> PV A-fragment is one full-bank b128 read; the P
// B-fragment stays lane-local (cvt_pk regs). defer-max rescale (THR=8).
// ---------------------------------------------------------------------------
__global__ __launch_bounds__(256, 4) void attn_kernel(const short* __restrict__ qbuf,
                                                      const short* __restrict__ kbuf,
                                                      const short* __restrict__ vtbuf,
                                                      short* __restrict__ ao) {
  __shared__ short k_sm[2][64 * 64];  // 2 x 8 KB, row = kv (128 B), XOR-swizzled
  __shared__ short v_sm[2][64 * 64];  // 2 x 8 KB, row = d (128 B), permuted+swizzled
  const int t = threadIdx.x, lane = t & 63, w = t >> 6;
  const int col = lane & 15, rg = lane >> 4;
  const int bh = blockIdx.x, qt = blockIdx.y;
  const int b = bh >> 3, h = bh & 7;
  const int qbase = qt * 128 + w * 32;

  // Q fragments (B-operand): aq[mf][kc], lane col = q, k = d
  bf16x8 aq[2][2];
  {
    const short* qp = qbuf + ((size_t)bh * 1024 + qbase) * 64;
#pragma unroll
    for (int mf = 0; mf < 2; ++mf)
#pragma unroll
      for (int kc = 0; kc < 2; ++kc)
        aq[mf][kc] = *(const bf16x8*)&qp[(mf * 16 + col) * 64 + kc * 32 + rg * 8];
  }

  const short* kp0 = kbuf + (size_t)bh * 65536;
  const short* vp0 = vtbuf + (size_t)bh * 65536;

  uint4 kr[2], vr[2];
#define LOADK(kt)                                                                  \
  _Pragma("unroll") for (int i = 0; i < 2; ++i) {                                  \
    int j = t + 256 * i;                                                           \
    kr[i] = *(const uint4*)&kp0[((size_t)(kt)*64 + (j >> 3)) * 64 + (j & 7) * 8];  \
  }
#define LOADV(kt)                                                                  \
  _Pragma("unroll") for (int i = 0; i < 2; ++i) {                                  \
    int j = t + 256 * i;                                                           \
    vr[i] = *(const uint4*)&vp0[(size_t)(j >> 3) * 1024 + (kt)*64 + (j & 7) * 8];  \
  }
#define WRITEK(bi)                                                                 \
  _Pragma("unroll") for (int i = 0; i < 2; ++i) {                                  \
    int j = t + 256 * i;                                                           \
    int row = j >> 3, off = j & 7;                                                 \
    *(uint4*)((char*)k_sm[bi] + row * 128 + ((off * 16) ^ ((row & 7) << 4))) = kr[i]; \
  }
#define WRITEV(bi)                                                                 \
  _Pragma("unroll") for (int i = 0; i < 2; ++i) {                                  \
    int j = t + 256 * i;                                                           \
    int d = j >> 3, g = j & 7;                                                     \
    int base = (g >> 2) * 64 + (g & 1) * 32 + ((g >> 1) & 1) * 8;                  \
    char* vb = (char*)v_sm[bi] + d * 128;                                          \
    uint2 lo = {vr[i].x, vr[i].y}, hi = {vr[i].z, vr[i].w};                        \
    *(uint2*)(vb + ((base) ^ ((d & 7) << 4))) = lo;                                \
    *(uint2*)(vb + ((base + 16) ^ ((d & 7) << 4))) = hi;                           \
  }

  LOADK(0) LOADV(0) WRITEK(0) WRITEV(0)

  f32x4 oacc[2][4] = {};
  float mrun[2] = {-3e38f, -3e38f}, lrun[2] = {0.f, 0.f};
  const float kSL2E = 0.125f * LOG2E;  // attn scale folded into log2 domain
  int cur = 0;

  for (int kt = 0; kt < 16; ++kt) {
    if (kt < 15) { LOADK(kt + 1) LOADV(kt + 1) }
    __syncthreads();

    // S^T = K * Q^T : K fragment read once, shared by both mf.
    f32x4 sT[2][4];
    __builtin_amdgcn_s_setprio(1);
#pragma unroll
    for (int nf = 0; nf < 4; ++nf) {
      const int n = nf * 16 + col;
      const char* kb = (const char*)k_sm[cur] + n * 128;
      const int sw = (n & 7) << 4;
      bf16x8 bk0 = *(const bf16x8*)(kb + ((rg * 16) ^ sw));
      bf16x8 bk1 = *(const bf16x8*)(kb + ((64 + rg * 16) ^ sw));
#pragma unroll
      for (int mf = 0; mf < 2; ++mf) {
        f32x4 z = {};
        z = MFMA16(bk0, aq[mf][0], z);
        sT[mf][nf] = MFMA16(bk1, aq[mf][1], z);
      }
    }
    __builtin_amdgcn_s_setprio(0);

    unsigned pk[2][4][2];
#pragma unroll
    for (int mf = 0; mf < 2; ++mf) {
      // online softmax: 4 parallel max chains + 2 cross-rg shuffles
      f32x4 mv = sT[mf][0];
#pragma unroll
      for (int nf = 1; nf < 4; ++nf)
#pragma unroll
        for (int r = 0; r < 4; ++r) mv[r] = fmaxf(mv[r], sT[mf][nf][r]);
      float mx = fmaxf(fmaxf(mv[0], mv[1]), fmaxf(mv[2], mv[3]));
      mx = fmaxf(mx, __shfl_xor(mx, 16));
      mx = fmaxf(mx, __shfl_xor(mx, 32));
      const float pmax = mx * 0.125f;
      // defer-max: only rescale when the running max grew by > 8
      if (!__all(pmax <= mrun[mf] + 8.f)) {
        const float mnew = fmaxf(mrun[mf], pmax);
        const float alpha = __builtin_amdgcn_exp2f((mrun[mf] - mnew) * LOG2E);
        mrun[mf] = mnew;
        lrun[mf] *= alpha;
#pragma unroll
        for (int df = 0; df < 4; ++df) oacc[mf][df] *= alpha;
      }
      const float nege = mrun[mf] * LOG2E;
      float psum = 0.f;
#pragma unroll
      for (int nf = 0; nf < 4; ++nf) {
        float p0 = __builtin_amdgcn_exp2f(fmaf(sT[mf][nf][0], kSL2E, -nege));
        float p1 = __builtin_amdgcn_exp2f(fmaf(sT[mf][nf][1], kSL2E, -nege));
        float p2 = __builtin_amdgcn_exp2f(fmaf(sT[mf][nf][2], kSL2E, -nege));
        float p3 = __builtin_amdgcn_exp2f(fmaf(sT[mf][nf][3], kSL2E, -nege));
        psum += (p0 + p1) + (p2 + p3);
        pk[mf][nf][0] = cvtpk(p0, p1);
        pk[mf][nf][1] = cvtpk(p2, p3);
      }
      psum += __shfl_xor(psum, 16);
      psum += __shfl_xor(psum, 32);
      lrun[mf] += psum;
    }

    // O^T += V^T * P^T : shared V b128 read feeds both Q-fragments' MFMAs
    __builtin_amdgcn_s_setprio(1);
#pragma unroll
    for (int kc = 0; kc < 2; ++kc) {
      bf16x8 pb[2];
#pragma unroll
      for (int mf = 0; mf < 2; ++mf) {
        u32x4 pbu = {pk[mf][2 * kc][0], pk[mf][2 * kc][1], pk[mf][2 * kc + 1][0],
                     pk[mf][2 * kc + 1][1]};
        pb[mf] = __builtin_bit_cast(bf16x8, pbu);
      }
#pragma unroll
      for (int df = 0; df < 4; ++df) {
        const int d = df * 16 + col;
        bf16x8 av = *(const bf16x8*)((const char*)v_sm[cur] + d * 128 +
                                     ((kc * 64 + rg * 16) ^ ((d & 7) << 4)));
#pragma unroll
        for (int mf = 0; mf < 2; ++mf) oacc[mf][df] = MFMA16(av, pb[mf], oacc[mf][df]);
      }
    }
    __builtin_amdgcn_s_setprio(0);

    if (kt < 15) { WRITEK(cur ^ 1) WRITEV(cur ^ 1) }
    cur ^= 1;
  }

  // epilogue: O[q][d = df*16 + rg*4 + r], lane-local 1/l scale
#pragma unroll
  for (int mf = 0; mf < 2; ++mf) {
    const float rl = 1.f / lrun[mf];
    const int q = qbase + mf * 16 + col;
    short* dst = ao + ((size_t)b * 1024 + q) * 512 + h * 64;
#pragma unroll
    for (int df = 0; df < 4; ++df) {
      short4v pkv;
#pragma unroll
      for (int r = 0; r < 4; ++r) pkv[r] = f2bf(oacc[mf][df][r] * rl);
      *(short4v*)&dst[df * 16 + rg * 4] = pkv;
    }
  }
#undef LOADK
#undef LOADV
#undef WRITEK
#undef WRITEV
}

// ---------------------------------------------------------------------------
// Proj GEMM + bias + fp32 residual: out = x + W_proj @ ao
// ---------------------------------------------------------------------------
__global__ __launch_bounds__(256) void proj_gemm(const short* __restrict__ W,
                                                 const short* __restrict__ ao,
                                                 const float* __restrict__ bias,
                                                 const float* __restrict__ x,
                                                 float* __restrict__ out) {
  __shared__ short a_sm[128 * 32];
  __shared__ short b_sm[128 * 32];
  const int t = threadIdx.x;
  const int lane = t & 63, w = t >> 6;
  const int nbase = blockIdx.x * 128;
  const int mbase = blockIdx.y * 128;
  const int b = blockIdx.z;
  const short* Asrc = W + (size_t)mbase * 512;
  const short* Bsrc = ao + (size_t)b * 1024 * 512 + (size_t)nbase * 512;

  const int j0 = (w * 2) * 64 + lane;
  const int j1 = j0 + 64;
  const int r0 = j0 >> 2, c0 = (j0 & 3) * 8;
  const int r1 = j1 >> 2, c1 = (j1 & 3) * 8;

  const int wm = (w >> 1) * 64, wn = (w & 1) * 64;
  const int col = lane & 15, rg = lane >> 4, koff = rg * 8;

  f32x4 acc[4][4] = {};

  for (int kt = 0; kt < 16; ++kt) {
    const int k0 = kt * 32;
    g2l16(&a_sm[(w * 2) * 512], Asrc + (size_t)r0 * 512 + k0 + c0);
    g2l16(&a_sm[(w * 2 + 1) * 512], Asrc + (size_t)r1 * 512 + k0 + c1);
    g2l16(&b_sm[(w * 2) * 512], Bsrc + (size_t)r0 * 512 + k0 + c0);
    g2l16(&b_sm[(w * 2 + 1) * 512], Bsrc + (size_t)r1 * 512 + k0 + c1);
    __syncthreads();
    bf16x8 af[4], bfr[4];
    for (int mf = 0; mf < 4; ++mf)
      af[mf] = *(const bf16x8*)&a_sm[(wm + mf * 16 + col) * 32 + koff];
    for (int nf = 0; nf < 4; ++nf)
      bfr[nf] = *(const bf16x8*)&b_sm[(wn + nf * 16 + col) * 32 + koff];
    for (int mf = 0; mf < 4; ++mf)
      for (int nf = 0; nf < 4; ++nf)
        acc[mf][nf] = MFMA16(af[mf], bfr[nf], acc[mf][nf]);
    __syncthreads();
  }

  for (int mf = 0; mf < 4; ++mf) {
    const int o0 = mbase + wm + mf * 16 + rg * 4;
    float b4[4];
    for (int r = 0; r < 4; ++r) b4[r] = bias[o0 + r];
    for (int nf = 0; nf < 4; ++nf) {
      const int n = nbase + wn + nf * 16 + col;
      for (int r = 0; r < 4; ++r) {
        size_t idx = ((size_t)b * 512 + o0 + r) * 1024 + n;
        out[idx] = x[idx] + acc[mf][nf][r] + b4[r];
      }
    }
  }
}

// ---------------------------------------------------------------------------
extern "C" void kernel_launch(void* const* d_in, const int* in_sizes, int n_in,
                              void* d_out, int out_size, void* d_ws, size_t ws_size,
                              hipStream_t stream) {
  const float* x = (const float*)d_in[0];
  const float* gamma = (const float*)d_in[1];
  const float* beta = (const float*)d_in[2];
  const float* w_qkv = (const float*)d_in[3];
  const float* b_qkv = (const float*)d_in[4];
  const float* w_proj = (const float*)d_in[5];
  const float* b_proj = (const float*)d_in[6];
  float* out = (float*)d_out;

  char* ws = (char*)d_ws;
  short* xn_t = (short*)(ws);                  // 8 MB   (B,N,C) bf16
  short* wqkv_b = (short*)(ws + 8388608);      // 1.5 MB
  short* wproj_b = (short*)(ws + 9961472);     // 0.5 MB
  short* qbuf = (short*)(ws + 10485760);       // 8 MB   (BH,N,d)
  short* kbuf = (short*)(ws + 18874368);       // 8 MB   (BH,N,d)
  short* vtbuf = (short*)(ws + 27262976);      // 8 MB   (BH,d,N)
  short* aobuf = (short*)(ws + 35651584);      // 8 MB   (B,N,C)

  gn_kernel<<<dim3(256), dim3(256), 0, stream>>>(x, gamma, beta, xn_t);
  f2bf_kernel<<<dim3(768), dim3(256), 0, stream>>>(w_qkv, wqkv_b, 196608);
  f2bf_kernel<<<dim3(256), dim3(256), 0, stream>>>(w_proj, wproj_b, 65536);
  qkv_gemm<<<dim3(8, 12, 8), dim3(256), 0, stream>>>(wqkv_b, xn_t, b_qkv, qbuf, kbuf,
                                                     vtbuf);
  attn_kernel<<<dim3(64, 8), dim3(256), 0, stream>>>(qbuf, kbuf, vtbuf, aobuf);
  proj_gemm<<<dim3(8, 4, 8), dim3(256), 0, stream>>>(wproj_b, aobuf, b_proj, x, out);
}

// Round 7
// 86.757 us; speedup vs baseline: 1.3432x; 1.1116x over previous
//
#include <hip/hip_runtime.h>

#define LOG2E 1.4426950408889634f

typedef short bf16x8 __attribute__((ext_vector_type(8)));
typedef short short4v __attribute__((ext_vector_type(4)));
typedef float f32x4 __attribute__((ext_vector_type(4)));
typedef _Float16 half4v __attribute__((ext_vector_type(4)));
typedef unsigned u32x4 __attribute__((ext_vector_type(4)));
typedef unsigned __attribute__((address_space(1))) u32g;
typedef unsigned __attribute__((address_space(3))) u32l;

#define MFMA16(a, b, c) __builtin_amdgcn_mfma_f32_16x16x32_bf16((a), (b), (c), 0, 0, 0)

__device__ __forceinline__ short f2bf(float f) {
  unsigned u = __builtin_bit_cast(unsigned, f);
  u += 0x7FFFu + ((u >> 16) & 1u);
  return (short)(u >> 16);
}

__device__ __forceinline__ unsigned cvtpk(float lo, float hi) {
  unsigned r;
  asm("v_cvt_pk_bf16_f32 %0, %1, %2" : "=v"(r) : "v"(lo), "v"(hi));
  return r;
}

__device__ __forceinline__ void g2l16(void* lds, const void* g) {
  __builtin_amdgcn_global_load_lds((u32g*)const_cast<void*>(g), (u32l*)lds, 16, 0, 0);
}

// ---------------------------------------------------------------------------
// GroupNorm: x (B,512,1024) f32 -> xn_t (B,1024,512) bf16   [transposed for GEMM]
// ---------------------------------------------------------------------------
__global__ __launch_bounds__(256) void gn_kernel(const float* __restrict__ x,
                                                 const float* __restrict__ gamma,
                                                 const float* __restrict__ beta,
                                                 short* __restrict__ xn_t) {
  __shared__ _Float16 xs[16 * 1024];  // 32 KB, row = channel, swizzled
  __shared__ float red[8];
  const int bg = blockIdx.x;
  const int b = bg >> 5, g = bg & 31;
  const int t = threadIdx.x;
  const float4* gx4 = (const float4*)(x + (size_t)(b * 512 + g * 16) * 1024);
  float s1 = 0.f, s2 = 0.f;
  for (int i = 0; i < 16; ++i) {
    float4 v = gx4[t + 256 * i];
    s1 += (v.x + v.y) + (v.z + v.w);
    s2 += (v.x * v.x + v.y * v.y) + (v.z * v.z + v.w * v.w);
    half4v pk = {(_Float16)v.x, (_Float16)v.y, (_Float16)v.z, (_Float16)v.w};
    *(half4v*)((char*)xs + i * 2048 + ((8 * t) ^ ((i & 7) << 4))) = pk;
  }
  for (int m = 1; m < 64; m <<= 1) {
    s1 += __shfl_xor(s1, m);
    s2 += __shfl_xor(s2, m);
  }
  if ((t & 63) == 0) {
    red[(t >> 6) * 2] = s1;
    red[(t >> 6) * 2 + 1] = s2;
  }
  __syncthreads();
  s1 = (red[0] + red[2]) + (red[4] + red[6]);
  s2 = (red[1] + red[3]) + (red[5] + red[7]);
  const float mean = s1 * (1.f / 16384.f);
  const float var = s2 * (1.f / 16384.f) - mean * mean;
  const float rstd = rsqrtf(var + 1e-6f);
  const int ci = t & 15;
  const float ga = gamma[g * 16 + ci] * rstd;
  const float be = beta[g * 16 + ci] - mean * ga;
  short* dst = xn_t + (size_t)b * 1024 * 512 + g * 16 + ci;
  const int sw = (ci & 7) << 4;
  for (int i = 0; i < 64; ++i) {
    int n = (t >> 4) + 16 * i;
    float v = (float)*(const _Float16*)((const char*)xs + ci * 2048 + ((2 * n) ^ sw));
    dst[(size_t)n * 512] = f2bf(fmaf(v, ga, be));
  }
}

// ---------------------------------------------------------------------------
__global__ __launch_bounds__(256) void f2bf_kernel(const float* __restrict__ src,
                                                   short* __restrict__ dst, int n4) {
  int i = blockIdx.x * 256 + threadIdx.x;
  if (i < n4) {
    float4 v = ((const float4*)src)[i];
    short4v o = {f2bf(v.x), f2bf(v.y), f2bf(v.z), f2bf(v.w)};
    *(short4v*)(dst + (size_t)i * 4) = o;
  }
}

// ---------------------------------------------------------------------------
// QKV GEMM, 2-phase prefetch: STAGE(kt+1) issued BEFORE compute(kt), one
// barrier per kt (T3-minimum). LDS chunk-XOR swizzle (chunk c of row stored
// at c ^ ((row>>1)&3)) applied via pre-swizzled global source (g2l16 dest is
// linear); fragment reads use the same XOR -> conflict-free ds_read_b128.
// ---------------------------------------------------------------------------
__global__ __launch_bounds__(256) void qkv_gemm(const short* __restrict__ W,
                                                const short* __restrict__ xn,
                                                const float* __restrict__ bias,
                                                short* __restrict__ qbuf,
                                                short* __restrict__ kbuf,
                                                short* __restrict__ vtbuf) {
  __shared__ short a_sm[2][128 * 32];
  __shared__ short b_sm[2][128 * 32];
  const int t = threadIdx.x;
  const int lane = t & 63, w = t >> 6;
  const int nbase = blockIdx.x * 128;
  const int mbase = blockIdx.y * 128;
  const int b = blockIdx.z;
  const short* Asrc = W + (size_t)mbase * 512;
  const short* Bsrc = xn + (size_t)b * 1024 * 512 + (size_t)nbase * 512;

  // staging: chunk j (16 B) -> row j>>2, lds chunk j&3, global chunk swizzled
  const int j0 = t, j1 = t + 256;
  const int r0 = j0 >> 2, c0 = ((j0 & 3) ^ ((j0 >> 3) & 3)) * 8;
  const int r1 = j1 >> 2, c1 = ((j1 & 3) ^ ((j1 >> 3) & 3)) * 8;

#define STAGE(bi, kt)                                                 \
  {                                                                   \
    const int k0s = (kt) * 32;                                        \
    g2l16(&a_sm[bi][j0 * 8], Asrc + (size_t)r0 * 512 + k0s + c0);     \
    g2l16(&a_sm[bi][j1 * 8], Asrc + (size_t)r1 * 512 + k0s + c1);     \
    g2l16(&b_sm[bi][j0 * 8], Bsrc + (size_t)r0 * 512 + k0s + c0);     \
    g2l16(&b_sm[bi][j1 * 8], Bsrc + (size_t)r1 * 512 + k0s + c1);     \
  }

  const int wm = (w >> 1) * 64, wn = (w & 1) * 64;
  const int col = lane & 15, rg = lane >> 4;

  f32x4 acc[4][4] = {};

  STAGE(0, 0)
  __syncthreads();
  int cur = 0;

  for (int kt = 0; kt < 16; ++kt) {
    if (kt < 15) STAGE(cur ^ 1, kt + 1);
    bf16x8 af[4], bfr[4];
#pragma unroll
    for (int mf = 0; mf < 4; ++mf) {
      const int row = wm + mf * 16 + col;
      af[mf] = *(const bf16x8*)&a_sm[cur][row * 32 + ((rg ^ ((row >> 1) & 3)) * 8)];
    }
#pragma unroll
    for (int nf = 0; nf < 4; ++nf) {
      const int row = wn + nf * 16 + col;
      bfr[nf] = *(const bf16x8*)&b_sm[cur][row * 32 + ((rg ^ ((row >> 1) & 3)) * 8)];
    }
    __builtin_amdgcn_s_setprio(1);
#pragma unroll
    for (int mf = 0; mf < 4; ++mf)
#pragma unroll
      for (int nf = 0; nf < 4; ++nf)
        acc[mf][nf] = MFMA16(af[mf], bfr[nf], acc[mf][nf]);
    __builtin_amdgcn_s_setprio(0);
    __syncthreads();
    cur ^= 1;
  }
#undef STAGE

  const int section = mbase >> 9;
  for (int mf = 0; mf < 4; ++mf) {
    const int o0 = mbase + wm + mf * 16 + rg * 4;
    const int h = (o0 >> 6) & 7, d0 = o0 & 63;
    float b4[4];
    for (int r = 0; r < 4; ++r) b4[r] = bias[o0 + r];
    for (int nf = 0; nf < 4; ++nf) {
      const int n = nbase + wn + nf * 16 + col;
      if (section < 2) {
        short4v pkv;
        for (int r = 0; r < 4; ++r) pkv[r] = f2bf(acc[mf][nf][r] + b4[r]);
        short* dst = (section == 0) ? qbuf : kbuf;
        *(short4v*)&dst[((size_t)(b * 8 + h) * 1024 + n) * 64 + d0] = pkv;
      } else {
        for (int r = 0; r < 4; ++r)
          vtbuf[((size_t)(b * 8 + h) * 64 + d0 + r) * 1024 + n] =
              f2bf(acc[mf][nf][r] + b4[r]);
      }
    }
  }
}

// ---------------------------------------------------------------------------
// Flash attention, swapped-operand, 32 q-rows/wave, 4-wave blocks, KV-tile 64,
// ONE-TILE-AHEAD PIPELINE: per kt { loads(kt+2)->regs; QK(kt+1) MFMA (indep);
// SM(kt) VALU; PV(kt) MFMA; writes(kt+2)->LDS; barrier }. Triple-buffered LDS
// (48 KB) so one barrier/kt suffices; sA/sB ping-pong via manual 2x unroll;
// buffer roles rotate through SGPR pointers. SM(kt) overlaps QK(kt+1) on
// separate pipes; loads get a full iteration of compute to land.
// ---------------------------------------------------------------------------
__global__ __launch_bounds__(256, 2) void attn_kernel(const short* __restrict__ qbuf,
                                                      const short* __restrict__ kbuf,
                                                      const short* __restrict__ vtbuf,
                                                      short* __restrict__ ao) {
  __shared__ short k_sm[3][64 * 64];  // 3 x 8 KB, row = kv (128 B), XOR-swizzled
  __shared__ short v_sm[3][64 * 64];  // 3 x 8 KB, row = d, permuted+swizzled
  const int t = threadIdx.x, lane = t & 63, w = t >> 6;
  const int col = lane & 15, rg = lane >> 4;
  const int bh = blockIdx.x, qt = blockIdx.y;
  const int b = bh >> 3, h = bh & 7;
  const int qbase = qt * 128 + w * 32;

  bf16x8 aq[2][2];
  {
    const short* qp = qbuf + ((size_t)bh * 1024 + qbase) * 64;
#pragma unroll
    for (int mf = 0; mf < 2; ++mf)
#pragma unroll
      for (int kc = 0; kc < 2; ++kc)
        aq[mf][kc] = *(const bf16x8*)&qp[(mf * 16 + col) * 64 + kc * 32 + rg * 8];
  }

  const short* kp0 = kbuf + (size_t)bh * 65536;
  const short* vp0 = vtbuf + (size_t)bh * 65536;

  uint4 kr[2], vr[2];
#define LOADK(kt)                                                                  \
  _Pragma("unroll") for (int i = 0; i < 2; ++i) {                                  \
    int j = t + 256 * i;                                                           \
    kr[i] = *(const uint4*)&kp0[((size_t)(kt)*64 + (j >> 3)) * 64 + (j & 7) * 8];  \
  }
#define LOADV(kt)                                                                  \
  _Pragma("unroll") for (int i = 0; i < 2; ++i) {                                  \
    int j = t + 256 * i;                                                           \
    vr[i] = *(const uint4*)&vp0[(size_t)(j >> 3) * 1024 + (kt)*64 + (j & 7) * 8];  \
  }
#define WRITEKP(dst)                                                               \
  _Pragma("unroll") for (int i = 0; i < 2; ++i) {                                  \
    int j = t + 256 * i;                                                           \
    int row = j >> 3, off = j & 7;                                                 \
    *(uint4*)((char*)(dst) + row * 128 + ((off * 16) ^ ((row & 7) << 4))) = kr[i]; \
  }
#define WRITEVP(dst)                                                               \
  _Pragma("unroll") for (int i = 0; i < 2; ++i) {                                  \
    int j = t + 256 * i;                                                           \
    int d = j >> 3, g = j & 7;                                                     \
    int base = (g >> 2) * 64 + (g & 1) * 32 + ((g >> 1) & 1) * 8;                  \
    char* vb = (char*)(dst) + d * 128;                                             \
    uint2 lo = {vr[i].x, vr[i].y}, hi = {vr[i].z, vr[i].w};                        \
    *(uint2*)(vb + ((base) ^ ((d & 7) << 4))) = lo;                                \
    *(uint2*)(vb + ((base + 16) ^ ((d & 7) << 4))) = hi;                           \
  }

  // QK(kt) from given K slot into sT
#define QKB(sT, kptr)                                                   \
  __builtin_amdgcn_s_setprio(1);                                        \
  _Pragma("unroll") for (int nf = 0; nf < 4; ++nf) {                    \
    const int n = nf * 16 + col;                                        \
    const char* kb = (const char*)(kptr) + n * 128;                     \
    const int sw = (n & 7) << 4;                                        \
    bf16x8 bk0 = *(const bf16x8*)(kb + ((rg * 16) ^ sw));               \
    bf16x8 bk1 = *(const bf16x8*)(kb + ((64 + rg * 16) ^ sw));          \
    _Pragma("unroll") for (int mf = 0; mf < 2; ++mf) {                  \
      f32x4 z = {};                                                     \
      z = MFMA16(bk0, aq[mf][0], z);                                    \
      sT[mf][nf] = MFMA16(bk1, aq[mf][1], z);                           \
    }                                                                   \
  }                                                                     \
  __builtin_amdgcn_s_setprio(0);

  // online softmax of sT -> pk (lane-local), lrun/mrun update, defer-max
#define SMB(sT)                                                             \
  _Pragma("unroll") for (int mf = 0; mf < 2; ++mf) {                        \
    f32x4 mv = sT[mf][0];                                                   \
    _Pragma("unroll") for (int nf = 1; nf < 4; ++nf)                        \
        _Pragma("unroll") for (int r = 0; r < 4; ++r)                       \
            mv[r] = fmaxf(mv[r], sT[mf][nf][r]);                            \
    float mx = fmaxf(fmaxf(mv[0], mv[1]), fmaxf(mv[2], mv[3]));             \
    mx = fmaxf(mx, __shfl_xor(mx, 16));                                     \
    mx = fmaxf(mx, __shfl_xor(mx, 32));                                     \
    const float pmax = mx * 0.125f;                                         \
    if (!__all(pmax <= mrun[mf] + 8.f)) {                                   \
      const float mnew = fmaxf(mrun[mf], pmax);                             \
      const float alpha = __builtin_amdgcn_exp2f((mrun[mf] - mnew) * LOG2E);\
      mrun[mf] = mnew;                                                      \
      lrun[mf] *= alpha;                                                    \
      _Pragma("unroll") for (int df = 0; df < 4; ++df) oacc[mf][df] *= alpha; \
    }                                                                       \
    const float nege = mrun[mf] * LOG2E;                                    \
    float psum = 0.f;                                                       \
    _Pragma("unroll") for (int nf = 0; nf < 4; ++nf) {                      \
      float p0 = __builtin_amdgcn_exp2f(fmaf(sT[mf][nf][0], kSL2E, -nege)); \
      float p1 = __builtin_amdgcn_exp2f(fmaf(sT[mf][nf][1], kSL2E, -nege)); \
      float p2 = __builtin_amdgcn_exp2f(fmaf(sT[mf][nf][2], kSL2E, -nege)); \
      float p3 = __builtin_amdgcn_exp2f(fmaf(sT[mf][nf][3], kSL2E, -nege)); \
      psum += (p0 + p1) + (p2 + p3);                                        \
      pk[mf][nf][0] = cvtpk(p0, p1);                                        \
      pk[mf][nf][1] = cvtpk(p2, p3);                                        \
    }                                                                       \
    psum += __shfl_xor(psum, 16);                                           \
    psum += __shfl_xor(psum, 32);                                           \
    lrun[mf] += psum;                                                       \
  }

#define PVB(vptr)                                                           \
  __builtin_amdgcn_s_setprio(1);                                            \
  _Pragma("unroll") for (int kc = 0; kc < 2; ++kc) {                        \
    bf16x8 pb[2];                                                           \
    _Pragma("unroll") for (int mf = 0; mf < 2; ++mf) {                      \
      u32x4 pbu = {pk[mf][2 * kc][0], pk[mf][2 * kc][1],                    \
                   pk[mf][2 * kc + 1][0], pk[mf][2 * kc + 1][1]};           \
      pb[mf] = __builtin_bit_cast(bf16x8, pbu);                             \
    }                                                                       \
    _Pragma("unroll") for (int df = 0; df < 4; ++df) {                      \
      const int d = df * 16 + col;                                          \
      bf16x8 av = *(const bf16x8*)((const char*)(vptr) + d * 128 +          \
                                   ((kc * 64 + rg * 16) ^ ((d & 7) << 4))); \
      _Pragma("unroll") for (int mf = 0; mf < 2; ++mf)                      \
          oacc[mf][df] = MFMA16(av, pb[mf], oacc[mf][df]);                  \
    }                                                                       \
  }                                                                         \
  __builtin_amdgcn_s_setprio(0);

#define ITER(kt, sTc, sTn)                                                  \
  {                                                                         \
    if ((kt) + 2 < 16) { LOADK((kt) + 2) LOADV((kt) + 2) }                  \
    if ((kt) + 1 < 16) { QKB(sTn, kQ) }                                     \
    SMB(sTc)                                                                \
    PVB(vP)                                                                 \
    if ((kt) + 2 < 16) { WRITEKP(kW) WRITEVP(vW) }                          \
    __syncthreads();                                                        \
    short* tk = kP; kP = kQ; kQ = kW; kW = tk;                              \
    short* tv = vP; vP = vQ; vQ = vW; vW = tv;                              \
  }

  f32x4 oacc[2][4] = {};
  float mrun[2] = {-3e38f, -3e38f}, lrun[2] = {0.f, 0.f};
  const float kSL2E = 0.125f * LOG2E;
  unsigned pk[2][4][2];
  f32x4 sA[2][4], sB[2][4];

  // buffer roles at kt: vP/kP = slot kt%3 (PV read), kQ = (kt+1)%3 (QK read),
  // kW/vW = (kt+2)%3 (write target)
  short *kP = k_sm[0], *kQ = k_sm[1], *kW = k_sm[2];
  short *vP = v_sm[0], *vQ = v_sm[1], *vW = v_sm[2];

  // prologue: tile0 -> slot0, tile1 -> slot1, sA = sT(0)
  LOADK(0) LOADV(0)
  WRITEKP(kP) WRITEVP(vP)
  LOADK(1) LOADV(1)
  __syncthreads();
  QKB(sA, kP)
  WRITEKP(kQ) WRITEVP(vQ)
  __syncthreads();

  for (int kt2 = 0; kt2 < 16; kt2 += 2) {
    ITER(kt2, sA, sB)
    ITER(kt2 + 1, sB, sA)
  }

  // epilogue: O[q][d = df*16 + rg*4 + r], lane-local 1/l scale
#pragma unroll
  for (int mf = 0; mf < 2; ++mf) {
    const float rl = 1.f / lrun[mf];
    const int q = qbase + mf * 16 + col;
    short* dst = ao + ((size_t)b * 1024 + q) * 512 + h * 64;
#pragma unroll
    for (int df = 0; df < 4; ++df) {
      short4v pkv;
#pragma unroll
      for (int r = 0; r < 4; ++r) pkv[r] = f2bf(oacc[mf][df][r] * rl);
      *(short4v*)&dst[df * 16 + rg * 4] = pkv;
    }
  }
#undef LOADK
#undef LOADV
#undef WRITEKP
#undef WRITEVP
#undef QKB
#undef SMB
#undef PVB
#undef ITER
}

// ---------------------------------------------------------------------------
// Proj GEMM + bias + fp32 residual, 2-phase prefetch + swizzle, BM=64 tile
// (grid 512 blocks = 2 blocks/CU).
// ---------------------------------------------------------------------------
__global__ __launch_bounds__(256) void proj_gemm(const short* __restrict__ W,
                                                 const short* __restrict__ ao,
                                                 const float* __restrict__ bias,
                                                 const float* __restrict__ x,
                                                 float* __restrict__ out) {
  __shared__ short a_sm[2][64 * 32];
  __shared__ short b_sm[2][128 * 32];
  const int t = threadIdx.x;
  const int lane = t & 63, w = t >> 6;
  const int nbase = blockIdx.x * 128;
  const int mbase = blockIdx.y * 64;
  const int b = blockIdx.z;
  const short* Asrc = W + (size_t)mbase * 512;
  const short* Bsrc = ao + (size_t)b * 1024 * 512 + (size_t)nbase * 512;

  const int j0 = t, j1 = t + 256;
  const int r0 = j0 >> 2, c0 = ((j0 & 3) ^ ((j0 >> 3) & 3)) * 8;
  const int r1 = j1 >> 2, c1 = ((j1 & 3) ^ ((j1 >> 3) & 3)) * 8;

#define STAGE(bi, kt)                                                 \
  {                                                                   \
    const int k0s = (kt) * 32;                                        \
    g2l16(&a_sm[bi][j0 * 8], Asrc + (size_t)r0 * 512 + k0s + c0);     \
    g2l16(&b_sm[bi][j0 * 8], Bsrc + (size_t)r0 * 512 + k0s + c0);     \
    g2l16(&b_sm[bi][j1 * 8], Bsrc + (size_t)r1 * 512 + k0s + c1);     \
  }

  const int wm = (w >> 1) * 32, wn = (w & 1) * 64;
  const int col = lane & 15, rg = lane >> 4;

  f32x4 acc[2][4] = {};

  STAGE(0, 0)
  __syncthreads();
  int cur = 0;

  for (int kt = 0; kt < 16; ++kt) {
    if (kt < 15) STAGE(cur ^ 1, kt + 1);
    bf16x8 af[2], bfr[4];
#pragma unroll
    for (int mf = 0; mf < 2; ++mf) {
      const int row = wm + mf * 16 + col;
      af[mf] = *(const bf16x8*)&a_sm[cur][row * 32 + ((rg ^ ((row >> 1) & 3)) * 8)];
    }
#pragma unroll
    for (int nf = 0; nf < 4; ++nf) {
      const int row = wn + nf * 16 + col;
      bfr[nf] = *(const bf16x8*)&b_sm[cur][row * 32 + ((rg ^ ((row >> 1) & 3)) * 8)];
    }
    __builtin_amdgcn_s_setprio(1);
#pragma unroll
    for (int mf = 0; mf < 2; ++mf)
#pragma unroll
      for (int nf = 0; nf < 4; ++nf)
        acc[mf][nf] = MFMA16(af[mf], bfr[nf], acc[mf][nf]);
    __builtin_amdgcn_s_setprio(0);
    __syncthreads();
    cur ^= 1;
  }
#undef STAGE

  for (int mf = 0; mf < 2; ++mf) {
    const int o0 = mbase + wm + mf * 16 + rg * 4;
    float b4[4];
    for (int r = 0; r < 4; ++r) b4[r] = bias[o0 + r];
    for (int nf = 0; nf < 4; ++nf) {
      const int n = nbase + wn + nf * 16 + col;
      for (int r = 0; r < 4; ++r) {
        size_t idx = ((size_t)b * 512 + o0 + r) * 1024 + n;
        out[idx] = x[idx] + acc[mf][nf][r] + b4[r];
      }
    }
  }
}

// ---------------------------------------------------------------------------
extern "C" void kernel_launch(void* const* d_in, const int* in_sizes, int n_in,
                              void* d_out, int out_size, void* d_ws, size_t ws_size,
                              hipStream_t stream) {
  const float* x = (const float*)d_in[0];
  const float* gamma = (const float*)d_in[1];
  const float* beta = (const float*)d_in[2];
  const float* w_qkv = (const float*)d_in[3];
  const float* b_qkv = (const float*)d_in[4];
  const float* w_proj = (const float*)d_in[5];
  const float* b_proj = (const float*)d_in[6];
  float* out = (float*)d_out;

  char* ws = (char*)d_ws;
  short* xn_t = (short*)(ws);                  // 8 MB   (B,N,C) bf16
  short* wqkv_b = (short*)(ws + 8388608);      // 1.5 MB
  short* wproj_b = (short*)(ws + 9961472);     // 0.5 MB
  short* qbuf = (short*)(ws + 10485760);       // 8 MB   (BH,N,d)
  short* kbuf = (short*)(ws + 18874368);       // 8 MB   (BH,N,d)
  short* vtbuf = (short*)(ws + 27262976);      // 8 MB   (BH,d,N)
  short* aobuf = (short*)(ws + 35651584);      // 8 MB   (B,N,C)

  gn_kernel<<<dim3(256), dim3(256), 0, stream>>>(x, gamma, beta, xn_t);
  f2bf_kernel<<<dim3(768), dim3(256), 0, stream>>>(w_qkv, wqkv_b, 196608);
  f2bf_kernel<<<dim3(256), dim3(256), 0, stream>>>(w_proj, wproj_b, 65536);
  qkv_gemm<<<dim3(8, 12, 8), dim3(256), 0, stream>>>(wqkv_b, xn_t, b_qkv, qbuf, kbuf,
                                                     vtbuf);
  attn_kernel<<<dim3(64, 8), dim3(256), 0, stream>>>(qbuf, kbuf, vtbuf, aobuf);
  proj_gemm<<<dim3(8, 8, 8), dim3(256), 0, stream>>>(wproj_b, aobuf, b_proj, x, out);
}